// Round 1
// baseline (955.838 us; speedup 1.0000x reference)
//
#include <hip/hip_runtime.h>
#include <hip/hip_bf16.h>
#include <cstdint>

#define DI __device__ __forceinline__

using bf16x8 = __attribute__((ext_vector_type(8))) short;
using f32x4  = __attribute__((ext_vector_type(4))) float;

constexpr int IN_DIM = 384;
constexpr int HID    = 512;
constexpr int KTOT   = IN_DIM * 20;      // 7680: k = i*20 + t; t==0 -> silu, t-1 -> spline coef c
constexpr int BM = 64, BN = 128, BK = 160;   // 8 input dims per K-step
constexpr int NSTEP = KTOT / BK;             // 48
constexpr int A_STRIDE_B = 384;              // LDS bytes per A row (192 bf16, 160 used; 128B-multiple for swizzle)
constexpr int B_STRIDE_B = 320;              // LDS bytes per B row (160 bf16, linear for global_load_lds)

DI unsigned short f2bf(float f) {
  union { float f; uint32_t u; } v; v.f = f;
  uint32_t r = (v.u + 0x7FFFu + ((v.u >> 16) & 1u)) >> 16;
  return (unsigned short)r;
}
DI float b2f(uint32_t bits16) {
  union { uint32_t u; float f; } v; v.u = bits16 << 16; return v.f;
}
DI float fast_tanh(float x) {          // 1 - 2/(e^{2x}+1); exact at +-inf, monotone, ~1e-6 rel err
  float e = __expf(2.0f * x);
  return 1.0f - 2.0f / (e + 1.0f);
}
// st_16x32-style XOR swizzle on LDS byte offsets (rows are 128B-multiples)
DI uint32_t swz(uint32_t L) { return L ^ (((L >> 9) & 1u) << 5); }

#define GLOAD_LDS16(g, l)                                                        \
  __builtin_amdgcn_global_load_lds((const __attribute__((address_space(1))) void*)(g), \
                                   (__attribute__((address_space(3))) void*)(l), 16, 0, 0)

// ---------------- pack base_weight + spline_weight -> bf16 W[o][k], k = i*20 + t ----------------
__global__ __launch_bounds__(256) void kpack(const float* __restrict__ bw,
                                             const float* __restrict__ sw,
                                             unsigned short* __restrict__ Wb) {
  int idx = blockIdx.x * 256 + threadIdx.x;      // idx = o*384 + i ; W offset = idx*20
  const float* s = sw + (size_t)idx * 19;
  unsigned short* d = Wb + (size_t)idx * 20;
  d[0] = f2bf(bw[idx]);
#pragma unroll
  for (int c = 0; c < 19; ++c) d[1 + c] = f2bf(s[c]);
}

// ---------------- fused KAN GEMM: h[b][o] = tanh( A(x) @ W^T ) ----------------
__global__ __launch_bounds__(256) void kgemm1(const float* __restrict__ z,
                                              const float* __restrict__ ms,
                                              const float* __restrict__ md,
                                              const unsigned short* __restrict__ Wb,
                                              unsigned short* __restrict__ hout) {
  __shared__ short lds[32768];               // 64 KiB total: A [0,24576)B, B [24576,65536)B
  char* AsB = (char*)lds;
  char* BsB = (char*)lds + 24576;

  const int tid  = threadIdx.x;
  const int lane = tid & 63;
  const int wv   = tid >> 6;                 // 0..3 (waves tile N)
  const int l16  = lane & 15;
  const int lhi  = lane >> 4;                // 0..3

  // XCD-aware swizzle: grid 2048 = 8*256; each XCD pair shares one N-block -> W slice L2-resident
  int wg = blockIdx.x;
  int id = (wg & 7) * 256 + (wg >> 3);
  const int mblk = id & 511;
  const int nblk = id >> 9;
  const int row0 = mblk * BM;
  const int col0 = nblk * BN;

  f32x4 acc[4][2] = {};

  for (int s = 0; s < NSTEP; ++s) {
    // ---- stage B: 128 rows x 320B = 2560 16B chunks, async global->LDS
#pragma unroll
    for (int rr = 0; rr < 10; ++rr) {
      int chunk = rr * 256 + tid;
      int o  = chunk / 20;
      int sl = chunk - o * 20;
      const unsigned short* g = Wb + (size_t)(col0 + o) * KTOT + s * BK + sl * 8;
      GLOAD_LDS16(g, BsB + chunk * 16);
    }
    // ---- stage A: generate 64 rows x 8 input dims, 20 entries each (silu + 4 nonzero bases)
#pragma unroll
    for (int r = 0; r < 2; ++r) {
      int task = tid + r * 256;              // 512 tasks
      int arow = task >> 3;                  // 0..63
      int isl  = task & 7;                   // 0..7
      int i    = s * 8 + isl;                // global input dim (source select uniform per step)
      const float* src = (i < 128) ? z : (i < 256 ? ms : md);
      float x  = src[(size_t)(row0 + arow) * 128 + (i & 127)];
      float xt = fast_tanh(x);
      float tt = (xt + 1.0f) * 8.0f;         // in [0,16]
      int   m  = (int)tt; m = m > 16 ? 16 : m;
      float u  = tt - (float)m;
      float omu = 1.0f - u;
      float u2 = u * u, u3 = u2 * u;
      float w0 = omu * omu * omu * (1.0f / 6.0f);
      float w1 = (3.0f * u3 - 6.0f * u2 + 4.0f) * (1.0f / 6.0f);
      float w2 = (-3.0f * u3 + 3.0f * u2 + 3.0f * u + 1.0f) * (1.0f / 6.0f);
      float w3 = u3 * (1.0f / 6.0f);
      float sil = xt / (1.0f + __expf(-xt));
      uint32_t base = (uint32_t)arow * A_STRIDE_B + isl * 40;
      // zero the 20-entry segment, then scatter the <=5 nonzeros
#pragma unroll
      for (int zz = 0; zz < 5; ++zz)
        *(uint64_t*)(AsB + swz(base + zz * 8)) = 0ull;
      *(short*)(AsB + swz(base)) = (short)f2bf(sil);                 // t = 0
      *(short*)(AsB + swz(base + 2u * (m + 1))) = (short)f2bf(w0);   // c = m
      *(short*)(AsB + swz(base + 2u * (m + 2))) = (short)f2bf(w1);
      *(short*)(AsB + swz(base + 2u * (m + 3))) = (short)f2bf(w2);
      if (m < 16)                                                     // c = m+3 (drop c==19)
        *(short*)(AsB + swz(base + 2u * (m + 4))) = (short)f2bf(w3);
    }
    __syncthreads();
    // ---- compute: 5 K-sub-steps of 32
    const uint32_t bbase = (uint32_t)(wv * 32) * B_STRIDE_B;
#pragma unroll
    for (int ks = 0; ks < 5; ++ks) {
      bf16x8 af[4], bfr[2];
#pragma unroll
      for (int mi = 0; mi < 4; ++mi) {
        uint32_t L = (uint32_t)(mi * 16 + l16) * A_STRIDE_B + ks * 64 + lhi * 16;
        af[mi] = *(const bf16x8*)(AsB + swz(L));
      }
#pragma unroll
      for (int ni = 0; ni < 2; ++ni) {
        uint32_t L = bbase + (uint32_t)(ni * 16 + l16) * B_STRIDE_B + ks * 64 + lhi * 16;
        bfr[ni] = *(const bf16x8*)(BsB + L);
      }
#pragma unroll
      for (int mi = 0; mi < 4; ++mi)
#pragma unroll
        for (int ni = 0; ni < 2; ++ni)
          acc[mi][ni] = __builtin_amdgcn_mfma_f32_16x16x32_bf16(af[mi], bfr[ni], acc[mi][ni], 0, 0, 0);
    }
    __syncthreads();
  }
  // ---- epilogue: tanh -> bf16 h
#pragma unroll
  for (int mi = 0; mi < 4; ++mi)
#pragma unroll
    for (int ni = 0; ni < 2; ++ni)
#pragma unroll
      for (int rg = 0; rg < 4; ++rg) {
        int grow = row0 + mi * 16 + lhi * 4 + rg;
        int gcol = col0 + wv * 32 + ni * 16 + l16;
        hout[(size_t)grow * HID + gcol] = f2bf(fast_tanh(acc[mi][ni][rg]));
      }
}

// ---------------- out[b][n] = h[b][:] . lin_w[n][:] + lin_b[n] ----------------
__global__ __launch_bounds__(256) void kfinal(const unsigned short* __restrict__ h,
                                              const float* __restrict__ lw,
                                              const float* __restrict__ lb,
                                              float* __restrict__ out) {
  int tid = threadIdx.x;
  int b = blockIdx.x * 4 + (tid >> 6);
  int n = tid & 63;
  const unsigned short* hr = h + (size_t)b * HID;
  const float* wr = lw + (size_t)n * HID;
  float acc = 0.f;
#pragma unroll 8
  for (int o = 0; o < HID; o += 8) {
    uint4 hv = *(const uint4*)(hr + o);
    float4 wa = *(const float4*)(wr + o);
    float4 wb = *(const float4*)(wr + o + 4);
    acc += b2f(hv.x & 0xFFFFu) * wa.x + b2f(hv.x >> 16) * wa.y;
    acc += b2f(hv.y & 0xFFFFu) * wa.z + b2f(hv.y >> 16) * wa.w;
    acc += b2f(hv.z & 0xFFFFu) * wb.x + b2f(hv.z >> 16) * wb.y;
    acc += b2f(hv.w & 0xFFFFu) * wb.z + b2f(hv.w >> 16) * wb.w;
  }
  out[(size_t)b * 64 + n] = acc + lb[n];
}

extern "C" void kernel_launch(void* const* d_in, const int* in_sizes, int n_in,
                              void* d_out, int out_size, void* d_ws, size_t ws_size,
                              hipStream_t stream) {
  const float* z  = (const float*)d_in[0];
  const float* ms = (const float*)d_in[1];
  const float* md = (const float*)d_in[2];
  const float* bw = (const float*)d_in[3];
  const float* sw = (const float*)d_in[4];
  const float* lw = (const float*)d_in[5];
  const float* lb = (const float*)d_in[6];
  float* out = (float*)d_out;

  unsigned short* Wb = (unsigned short*)d_ws;                        // 7.5 MiB: bf16 W [512][7680]
  unsigned short* hb = (unsigned short*)((char*)d_ws + (8u << 20));  // 32 MiB: bf16 h [32768][512]

  kpack<<<(HID * IN_DIM) / 256, 256, 0, stream>>>(bw, sw, Wb);
  kgemm1<<<2048, 256, 0, stream>>>(z, ms, md, Wb, hb);
  kfinal<<<32768 / 4, 256, 0, stream>>>(hb, lw, lb, out);
}

// Round 2
// 466.288 us; speedup vs baseline: 2.0499x; 2.0499x over previous
//
#include <hip/hip_runtime.h>
#include <hip/hip_bf16.h>
#include <cstdint>

#define DI __device__ __forceinline__

using bf16x8 = __attribute__((ext_vector_type(8))) short;
using f32x4  = __attribute__((ext_vector_type(4))) float;

constexpr int IN_DIM = 384;
constexpr int HID    = 512;
constexpr int KTOT   = IN_DIM * 20;      // 7680: k = i*20 + t; t==0 -> silu, t-1 -> spline coef c
constexpr int BM = 64, BN = 128, BK = 160;   // 8 input dims per K-step
constexpr int NSTEP = KTOT / BK;             // 48
constexpr int A_STRIDE_B = 384;              // LDS bytes per A row
constexpr int B_STRIDE_B = 320;              // LDS bytes per B row (linear for global_load_lds)

DI unsigned short f2bf(float f) {
  union { float f; uint32_t u; } v; v.f = f;
  uint32_t r = (v.u + 0x7FFFu + ((v.u >> 16) & 1u)) >> 16;
  return (unsigned short)r;
}
DI float fast_tanh(float x) {
  float e = __expf(2.0f * x);
  return 1.0f - 2.0f / (e + 1.0f);
}
DI uint32_t swz(uint32_t L) { return L ^ (((L >> 9) & 1u) << 5); }
// row-XOR swizzle for 1024B-stride LDS tiles: spread rows across 8 16B slots
DI uint32_t swzw(uint32_t L) { return L ^ ((L >> 6) & 0x70u); }

#define GLOAD_LDS16(g, l)                                                        \
  __builtin_amdgcn_global_load_lds((const __attribute__((address_space(1))) void*)(g), \
                                   (__attribute__((address_space(3))) void*)(l), 16, 0, 0)

// ---------------- pack base_weight + spline_weight -> bf16 W[o][k], k = i*20 + t ----------------
__global__ __launch_bounds__(256) void kpack(const float* __restrict__ bw,
                                             const float* __restrict__ sw,
                                             unsigned short* __restrict__ Wb) {
  int idx = blockIdx.x * 256 + threadIdx.x;      // idx = o*384 + i ; W offset = idx*20
  const float* s = sw + (size_t)idx * 19;
  unsigned short* d = Wb + (size_t)idx * 20;
  d[0] = f2bf(bw[idx]);
#pragma unroll
  for (int c = 0; c < 19; ++c) d[1 + c] = f2bf(s[c]);
}

// ---------------- fused KAN GEMM: h[b][o] = tanh( A(x) @ W^T ) ----------------
__global__ __launch_bounds__(256) void kgemm1(const float* __restrict__ z,
                                              const float* __restrict__ ms,
                                              const float* __restrict__ md,
                                              const unsigned short* __restrict__ Wb,
                                              unsigned short* __restrict__ hout) {
  __shared__ short lds[32768];               // 64 KiB total: A [0,24576)B, B [24576,65536)B
  char* AsB = (char*)lds;
  char* BsB = (char*)lds + 24576;

  const int tid  = threadIdx.x;
  const int lane = tid & 63;
  const int wv   = tid >> 6;                 // 0..3 (waves tile N)
  const int l16  = lane & 15;
  const int lhi  = lane >> 4;                // 0..3

  // XCD-aware swizzle: grid 2048 = 8*256; nblk locality within XCD -> W slice L2-resident
  int wg = blockIdx.x;
  int id = (wg & 7) * 256 + (wg >> 3);
  const int mblk = id & 511;
  const int nblk = id >> 9;
  const int row0 = mblk * BM;
  const int col0 = nblk * BN;

  f32x4 acc[4][2] = {};

  for (int s = 0; s < NSTEP; ++s) {
    // ---- stage B: 128 rows x 320B = 2560 16B chunks, async global->LDS
#pragma unroll
    for (int rr = 0; rr < 10; ++rr) {
      int chunk = rr * 256 + tid;
      int o  = chunk / 20;
      int sl = chunk - o * 20;
      const unsigned short* g = Wb + (size_t)(col0 + o) * KTOT + s * BK + sl * 8;
      GLOAD_LDS16(g, BsB + chunk * 16);
    }
    // ---- stage A: generate 64 rows x 8 input dims, 20 entries each (silu + 4 nonzero bases)
#pragma unroll
    for (int r = 0; r < 2; ++r) {
      int task = tid + r * 256;              // 512 tasks
      int arow = task >> 3;                  // 0..63
      int isl  = task & 7;                   // 0..7
      int i    = s * 8 + isl;                // global input dim
      const float* src = (i < 128) ? z : (i < 256 ? ms : md);
      float x  = src[(size_t)(row0 + arow) * 128 + (i & 127)];
      float xt = fast_tanh(x);
      float tt = (xt + 1.0f) * 8.0f;         // in [0,16]
      int   m  = (int)tt; m = m > 16 ? 16 : m;
      float u  = tt - (float)m;
      float omu = 1.0f - u;
      float u2 = u * u, u3 = u2 * u;
      float w0 = omu * omu * omu * (1.0f / 6.0f);
      float w1 = (3.0f * u3 - 6.0f * u2 + 4.0f) * (1.0f / 6.0f);
      float w2 = (-3.0f * u3 + 3.0f * u2 + 3.0f * u + 1.0f) * (1.0f / 6.0f);
      float w3 = u3 * (1.0f / 6.0f);
      float sil = xt / (1.0f + __expf(-xt));
      uint32_t base = (uint32_t)arow * A_STRIDE_B + isl * 40;
#pragma unroll
      for (int zz = 0; zz < 5; ++zz)
        *(uint64_t*)(AsB + swz(base + zz * 8)) = 0ull;
      *(short*)(AsB + swz(base)) = (short)f2bf(sil);                 // t = 0
      *(short*)(AsB + swz(base + 2u * (m + 1))) = (short)f2bf(w0);   // c = m
      *(short*)(AsB + swz(base + 2u * (m + 2))) = (short)f2bf(w1);
      *(short*)(AsB + swz(base + 2u * (m + 3))) = (short)f2bf(w2);
      if (m < 16)                                                     // c = m+3 (drop c==19)
        *(short*)(AsB + swz(base + 2u * (m + 4))) = (short)f2bf(w3);
    }
    __syncthreads();
    // ---- compute: 5 K-sub-steps of 32
    const uint32_t bbase = (uint32_t)(wv * 32) * B_STRIDE_B;
#pragma unroll
    for (int ks = 0; ks < 5; ++ks) {
      bf16x8 af[4], bfr[2];
#pragma unroll
      for (int mi = 0; mi < 4; ++mi) {
        uint32_t L = (uint32_t)(mi * 16 + l16) * A_STRIDE_B + ks * 64 + lhi * 16;
        af[mi] = *(const bf16x8*)(AsB + swz(L));
      }
#pragma unroll
      for (int ni = 0; ni < 2; ++ni) {
        uint32_t L = bbase + (uint32_t)(ni * 16 + l16) * B_STRIDE_B + ks * 64 + lhi * 16;
        bfr[ni] = *(const bf16x8*)(BsB + L);
      }
#pragma unroll
      for (int mi = 0; mi < 4; ++mi)
#pragma unroll
        for (int ni = 0; ni < 2; ++ni)
          acc[mi][ni] = __builtin_amdgcn_mfma_f32_16x16x32_bf16(af[mi], bfr[ni], acc[mi][ni], 0, 0, 0);
    }
    __syncthreads();
  }
  // ---- epilogue: tanh -> bf16 h
#pragma unroll
  for (int mi = 0; mi < 4; ++mi)
#pragma unroll
    for (int ni = 0; ni < 2; ++ni)
#pragma unroll
      for (int rg = 0; rg < 4; ++rg) {
        int grow = row0 + mi * 16 + lhi * 4 + rg;
        int gcol = col0 + wv * 32 + ni * 16 + l16;
        hout[(size_t)grow * HID + gcol] = f2bf(fast_tanh(acc[mi][ni][rg]));
      }
}

// ---------------- kfinal (MFMA): out[128? no, 64 rows/block] = h @ lin_w^T + b ----------------
// Each block: 64 rows of h, all 64 output cols. lin_w staged fp32->bf16 in LDS (swizzled).
__global__ __launch_bounds__(256) void kfinal(const unsigned short* __restrict__ h,
                                              const float* __restrict__ lw,
                                              const float* __restrict__ lb,
                                              float* __restrict__ out) {
  __shared__ unsigned short Ws[64 * 512];    // 64 KiB, rows 1024B, XOR-swizzled via swzw()
  char* WsB = (char*)Ws;
  const int tid  = threadIdx.x;
  const int lane = tid & 63;
  const int wv   = tid >> 6;                 // wave -> 16-row strip
  const int l16  = lane & 15;
  const int lhi  = lane >> 4;
  const int row0 = blockIdx.x * 64;

  // stage lin_w [64][512] fp32 -> bf16 LDS; each thread 16 chunks of 8 shorts
#pragma unroll
  for (int it = 0; it < 16; ++it) {
    int c = it * 256 + tid;                  // wave-uniform row (c>>6), contiguous k
    int r = c >> 6;
    int k8 = (c & 63) * 8;
    const float* g = lw + r * 512 + k8;
    float4 f0 = *(const float4*)g;
    float4 f1 = *(const float4*)(g + 4);
    union { unsigned short s[8]; bf16x8 v; } u;
    u.s[0] = f2bf(f0.x); u.s[1] = f2bf(f0.y); u.s[2] = f2bf(f0.z); u.s[3] = f2bf(f0.w);
    u.s[4] = f2bf(f1.x); u.s[5] = f2bf(f1.y); u.s[6] = f2bf(f1.z); u.s[7] = f2bf(f1.w);
    *(bf16x8*)(WsB + swzw((uint32_t)r * 1024u + (uint32_t)k8 * 2u)) = u.v;
  }
  __syncthreads();

  const int arow = row0 + wv * 16 + l16;
  const unsigned short* ag = h + (size_t)arow * HID + lhi * 8;
  f32x4 acc[4] = {};
#pragma unroll
  for (int ks = 0; ks < 16; ++ks) {
    bf16x8 af = *(const bf16x8*)(ag + ks * 32);
#pragma unroll
    for (int ni = 0; ni < 4; ++ni) {
      uint32_t L = (uint32_t)(ni * 16 + l16) * 1024u + (uint32_t)(ks * 64 + lhi * 16);
      bf16x8 bfr = *(const bf16x8*)(WsB + swzw(L));
      acc[ni] = __builtin_amdgcn_mfma_f32_16x16x32_bf16(af, bfr, acc[ni], 0, 0, 0);
    }
  }
#pragma unroll
  for (int ni = 0; ni < 4; ++ni) {
    int col = ni * 16 + l16;
    float bias = lb[col];
#pragma unroll
    for (int rg = 0; rg < 4; ++rg) {
      int grow = row0 + wv * 16 + lhi * 4 + rg;
      out[(size_t)grow * 64 + col] = acc[ni][rg] + bias;
    }
  }
}

extern "C" void kernel_launch(void* const* d_in, const int* in_sizes, int n_in,
                              void* d_out, int out_size, void* d_ws, size_t ws_size,
                              hipStream_t stream) {
  const float* z  = (const float*)d_in[0];
  const float* ms = (const float*)d_in[1];
  const float* md = (const float*)d_in[2];
  const float* bw = (const float*)d_in[3];
  const float* sw = (const float*)d_in[4];
  const float* lw = (const float*)d_in[5];
  const float* lb = (const float*)d_in[6];
  float* out = (float*)d_out;

  unsigned short* Wb = (unsigned short*)d_ws;                        // 7.5 MiB: bf16 W [512][7680]
  unsigned short* hb = (unsigned short*)((char*)d_ws + (8u << 20));  // 32 MiB: bf16 h [32768][512]

  kpack<<<(HID * IN_DIM) / 256, 256, 0, stream>>>(bw, sw, Wb);
  kgemm1<<<2048, 256, 0, stream>>>(z, ms, md, Wb, hb);
  kfinal<<<32768 / 64, 256, 0, stream>>>(hb, lw, lb, out);
}